// Round 5
// baseline (62.183 us; speedup 1.0000x reference)
//
#include <hip/hip_runtime.h>
#include <math.h>

// Problem constants: b=64, seq=2048, hid=256
#define BATCH 64
#define SEQ   2048
#define HID   256
#define KNEG  63            // b - 1
#define SGRP  4             // consecutive s values per block (4 KB linear runs)

// loss denominator: b*200*(K+1)*4 = 3,276,800
#define INV_DENOM (1.0f / 3276800.0f)

__device__ __forceinline__ float dot4(const float4& u, const float4& v) {
  return u.x * v.x + u.y * v.y + u.z * v.z + u.w * v.w;
}
__device__ __forceinline__ void fma4(float4& acc, const float4& v, float s) {
  acc.x = fmaf(v.x, s, acc.x);
  acc.y = fmaf(v.y, s, acc.y);
  acc.z = fmaf(v.z, s, acc.z);
  acc.w = fmaf(v.w, s, acc.w);
}

// R5: s-blocked streaming. Block = 4 consecutive s x all 64 rows; wave owns
// 8 rows; per row it reads 4 KB CONTIGUOUS per input (4 wave-wide float4
// loads) instead of R4's 1KB-chunk-then-2MB-jump pattern. Theory: short
// scattered runs were costing DRAM efficiency (R1..R4 all ~52us regardless
// of VALU/DS edits; HBM at only ~2.8 TB/s with nothing else saturated).
//
// Occupancy is grid-limited (512 blocks x 8 waves = 16 waves/CU = 4/SIMD),
// so VGPR budget up to 128 is free: __launch_bounds__(512,4).
//
// Math identical to R1/R4 (absmax 0.0):
//   per s: D = sum_i <a_n,b_n>, S = sum_i a_n, T = sum_i b_n
//   partial[s] = (2b - (1.5 + 1/(2K))*D + <S,T>/(2K)) * INV_DENOM
__global__ __launch_bounds__(512, 4) void cosnce_per_s(
    const float* __restrict__ rs, const float* __restrict__ rt,
    float* __restrict__ partial) {
  const int s0   = blockIdx.x * SGRP;   // first s of this block
  const int tid  = threadIdx.x;         // 0..511
  const int wave = tid >> 6;            // 0..7
  const int lane = tid & 63;            // 0..63
  const int col  = lane * 4;            // hid element offset (lane's float4)

  float4 Sacc[SGRP], Tacc[SGRP];
  float  Dacc[SGRP];
#pragma unroll
  for (int k = 0; k < SGRP; ++k) {
    Sacc[k] = make_float4(0.f, 0.f, 0.f, 0.f);
    Tacc[k] = Sacc[k];
    Dacc[k] = 0.f;
  }

#pragma unroll 2
  for (int r = 0; r < 8; ++r) {
    const int    i  = wave * 8 + r;     // this wave's batch row
    const size_t bo = ((size_t)i * SEQ + s0) * HID + col;
    const float* pa = rs + bo;
    const float* pb = rt + bo;

    // 8 loads; the 4 per input are CONSECUTIVE 1KB wave-segments = 4KB linear
    float4 a[SGRP], b[SGRP];
#pragma unroll
    for (int k = 0; k < SGRP; ++k) a[k] = *(const float4*)(pa + k * HID);
#pragma unroll
    for (int k = 0; k < SGRP; ++k) b[k] = *(const float4*)(pb + k * HID);

    float ss[SGRP], tt[SGRP], st[SGRP];
#pragma unroll
    for (int k = 0; k < SGRP; ++k) {
      ss[k] = dot4(a[k], a[k]);
      tt[k] = dot4(b[k], b[k]);
      st[k] = dot4(a[k], b[k]);
    }

    // 12 independent 6-step butterflies over the full wave (good DS ILP)
#pragma unroll
    for (int off = 1; off <= 32; off <<= 1) {
#pragma unroll
      for (int k = 0; k < SGRP; ++k) {
        ss[k] += __shfl_xor(ss[k], off);
        tt[k] += __shfl_xor(tt[k], off);
        st[k] += __shfl_xor(st[k], off);
      }
    }

#pragma unroll
    for (int k = 0; k < SGRP; ++k) {
      // F.normalize: x / max(||x||,1e-12)  ->  rsq(max(ss,1e-24))
      const float inv_s = __builtin_amdgcn_rsqf(fmaxf(ss[k], 1e-24f));
      const float inv_t = __builtin_amdgcn_rsqf(fmaxf(tt[k], 1e-24f));
      Dacc[k] = fmaf(st[k], inv_s * inv_t, Dacc[k]);
      fma4(Sacc[k], a[k], inv_s);
      fma4(Tacc[k], b[k], inv_t);
    }
  }

  // Cross-wave combine via LDS (once per kernel; 64KB, 2 blocks/CU fits 160KB)
  __shared__ float S_sh[8][SGRP][HID];
  __shared__ float T_sh[8][SGRP][HID];
  __shared__ float D_sh[8][SGRP];

#pragma unroll
  for (int k = 0; k < SGRP; ++k) {
    *(float4*)&S_sh[wave][k][col] = Sacc[k];
    *(float4*)&T_sh[wave][k][col] = Tacc[k];
  }
  if (lane == 0) {
#pragma unroll
    for (int k = 0; k < SGRP; ++k) D_sh[wave][k] = Dacc[k];
  }
  __syncthreads();

  // waves 0..3 finalize one s each
  if (wave < SGRP) {
    const int k = wave;
    float4 Ssum = make_float4(0.f, 0.f, 0.f, 0.f), Tsum = Ssum;
#pragma unroll
    for (int w = 0; w < 8; ++w) {
      const float4 sv = *(const float4*)&S_sh[w][k][col];
      const float4 tv = *(const float4*)&T_sh[w][k][col];
      Ssum.x += sv.x; Ssum.y += sv.y; Ssum.z += sv.z; Ssum.w += sv.w;
      Tsum.x += tv.x; Tsum.y += tv.y; Tsum.z += tv.z; Tsum.w += tv.w;
    }
    float prod = dot4(Ssum, Tsum);
#pragma unroll
    for (int off = 1; off <= 32; off <<= 1) prod += __shfl_xor(prod, off);
    if (lane == 0) {
      float Dtot = 0.f;
#pragma unroll
      for (int w = 0; w < 8; ++w) Dtot += D_sh[w][k];
      const float inv2K = 1.f / (2.f * (float)KNEG);
      const float cres  = 2.f * (float)BATCH - (1.5f + inv2K) * Dtot + prod * inv2K;
      partial[s0 + k] = cres * INV_DENOM;
    }
  }
}

// Deterministic final reduction of SEQ partials -> scalar loss.
__global__ __launch_bounds__(256) void cosnce_reduce(
    const float* __restrict__ partial, float* __restrict__ out) {
  const int tid  = threadIdx.x;
  const int wave = tid >> 6;
  const int lane = tid & 63;
  float acc = 0.f;
  for (int idx = tid; idx < SEQ; idx += 256) acc += partial[idx];
#pragma unroll
  for (int off = 32; off > 0; off >>= 1) acc += __shfl_xor(acc, off);
  __shared__ float sh[4];
  if (lane == 0) sh[wave] = acc;
  __syncthreads();
  if (tid == 0) out[0] = sh[0] + sh[1] + sh[2] + sh[3];
}

extern "C" void kernel_launch(void* const* d_in, const int* in_sizes, int n_in,
                              void* d_out, int out_size, void* d_ws, size_t ws_size,
                              hipStream_t stream) {
  const float* rs = (const float*)d_in[0];   // r_s [64,2048,256] fp32
  const float* rt = (const float*)d_in[1];   // r_t [64,2048,256] fp32
  float* out      = (float*)d_out;           // scalar fp32 loss
  float* partial  = (float*)d_ws;            // SEQ floats of scratch

  cosnce_per_s<<<SEQ / SGRP, 512, 0, stream>>>(rs, rt, partial);
  cosnce_reduce<<<1, 256, 0, stream>>>(partial, out);
}